// Round 8
// baseline (353.418 us; speedup 1.0000x reference)
//
#include <hip/hip_runtime.h>
#include <hip/hip_bf16.h>
#include <cstdint>

typedef __bf16 bf16;
typedef __bf16 bf16x8 __attribute__((ext_vector_type(8)));
typedef float  f32x4  __attribute__((ext_vector_type(4)));

// ---------- new-path workspace layout (needs >= 140113920 B) ----------
#define N_ENCB   0u            // bf16 enc (written by GEMM nt==0 blocks): 128 MB
#define N_W1BT   134217728u    // 2 MB
#define N_C      136314880u    // 128 KB
#define N_E      136445952u    // 256 KB
#define N_ALPHA  136707072u    // 256 KB
#define N_CTXP   138016768u    // 2 MB
#define N_TOTAL  140113920ull

// ---------- old-path (fallback) layout ----------
#define O_W1BT   0u
#define O_C      2097152u
#define O_E      2228224u
#define O_ALPHA  2490368u
#define O_HIDP   2752512u
#define O_CTXP   3801088u

// ---------------- cvec = b1 ----------------
__global__ void k_cvec_init(const float* __restrict__ b1, float* __restrict__ cvec) {
    int i = blockIdx.x * 256 + threadIdx.x;
    cvec[i] = b1[i & 1023];
}

// ---------------- hid_proj: atomic accumulate into cvec ----------------
__global__ void k_hid_atomic(const float* __restrict__ hid, const float* __restrict__ W1,
                             float* __restrict__ cvec) {
    int e = blockIdx.x * 256 + threadIdx.x;
    int dch = blockIdx.y;
    float acc[32];
#pragma unroll
    for (int b = 0; b < 32; ++b) acc[b] = 0.f;
    int d0 = dch * 32;
#pragma unroll 4
    for (int dd = 0; dd < 32; ++dd) {
        int d = d0 + dd;
        float w = W1[(size_t)(1024 + d) * 1024 + e];
#pragma unroll
        for (int b = 0; b < 32; ++b) acc[b] += hid[b * 1024 + d] * w;
    }
#pragma unroll
    for (int b = 0; b < 32; ++b) atomicAdd(&cvec[b * 1024 + e], acc[b]);
}

// ---------------- fallback hid_proj ----------------
__global__ void k_hid_partial(const float* __restrict__ hid, const float* __restrict__ W1,
                              float* __restrict__ hidp) {
    int e = blockIdx.x * 256 + threadIdx.x;
    int dch = blockIdx.y;
    float acc[32];
#pragma unroll
    for (int b = 0; b < 32; ++b) acc[b] = 0.f;
    int d0 = dch * 128;
    for (int dd = 0; dd < 128; ++dd) {
        int d = d0 + dd;
        float w = W1[(size_t)(1024 + d) * 1024 + e];
#pragma unroll
        for (int b = 0; b < 32; ++b) acc[b] += hid[b * 1024 + d] * w;
    }
#pragma unroll
    for (int b = 0; b < 32; ++b) hidp[((size_t)dch * 32 + b) * 1024 + e] = acc[b];
}

__global__ void k_hid_reduce(const float* __restrict__ hidp, const float* __restrict__ b1,
                             float* __restrict__ cvec) {
    int i = blockIdx.x * 256 + threadIdx.x;
    int e = i & 1023;
    float s = b1[e];
#pragma unroll
    for (int dch = 0; dch < 8; ++dch) s += hidp[(size_t)dch * 32768 + i];
    cvec[i] = s;
}

// ---------------- W1_enc -> w1bt (n x k) bf16 ----------------
__global__ void k_w1t(const float* __restrict__ W1, bf16* __restrict__ w1bt) {
    __shared__ float tile[32][33];
    int tx = threadIdx.x, ty = threadIdx.y;
    int bx = blockIdx.x, by = blockIdx.y;
#pragma unroll
    for (int i = 0; i < 4; ++i)
        tile[ty + i * 8][tx] = W1[(size_t)(by * 32 + ty + i * 8) * 1024 + bx * 32 + tx];
    __syncthreads();
#pragma unroll
    for (int i = 0; i < 4; ++i)
        w1bt[(size_t)(bx * 32 + ty + i * 8) * 1024 + by * 32 + tx] = (bf16)tile[tx][ty + i * 8];
}

__device__ inline float fast_tanh(float x) {
    float e2 = __expf(2.f * x);
    return 1.f - 2.f / (e2 + 1.f);
}

// ====== persistent 256x256 bf16 GEMM, 8-phase, A reg-staged from f32 (fused convert) ======
#define SBAR   __builtin_amdgcn_s_barrier()
#define LGKM0  asm volatile("s_waitcnt lgkmcnt(0)" ::: "memory")
#define VMC4   asm volatile("s_waitcnt vmcnt(4)" ::: "memory")
#define PRIO1  __builtin_amdgcn_s_setprio(1)
#define PRIO0  __builtin_amdgcn_s_setprio(0)

template<int D, int MH>
__device__ __forceinline__ void rdA4(const char* p, bf16x8 (&o)[4]) {
#pragma unroll
    for (int m = 0; m < 4; ++m)
        o[m] = *(const bf16x8*)(p + D * 32768 + MH * 8192 + m * 2048);
}
template<int D>
__device__ __forceinline__ void rdB4(const char* p, bf16x8 (&o)[4]) {
#pragma unroll
    for (int n = 0; n < 4; ++n)
        o[n] = *(const bf16x8*)(p + D * 32768 + n * 2048);
}
template<int MH>
__device__ __forceinline__ void mfma16(bf16x8 (&fa)[4], bf16x8 (&fb)[4], f32x4 (&acc)[8][4]) {
#pragma unroll
    for (int m = 0; m < 4; ++m)
#pragma unroll
        for (int n = 0; n < 4; ++n)
            acc[MH * 4 + m][n] = __builtin_amdgcn_mfma_f32_16x16x32_bf16(
                fa[m], fb[n], acc[MH * 4 + m][n], 0, 0, 0);
}

__global__ __launch_bounds__(512, 1) void k_gemm8(
    const float* __restrict__ encf, const bf16* __restrict__ w1bt,
    const float* __restrict__ cvec, const float* __restrict__ w2,
    float* __restrict__ ebuf, bf16* __restrict__ encb)
{
    __shared__ __align__(16) char smem[131072];
    const int t = threadIdx.x;
    const int lane = t & 63;
    const int w  = t >> 6;
    const int wr = w >> 2;
    const int wc = w & 3;
    const int l15 = lane & 15, g = (lane >> 4) & 3;

    unsigned bidx = blockIdx.x;               // 256 blocks
    unsigned swz0 = (bidx & 7u) * 128u + (bidx >> 3);
    const int nt  = swz0 & 3;
    const int mt0 = swz0 >> 2;
    const int n0  = nt * 256;
    const bool wb = (nt == 0);                // this block writes encb

    // --- A reg-staging geometry: half-tile = 128 rows x 64 K (128 B bf16/row) ---
    // Thread t owns row (t>>2) of the half, phys 16B slots q0,q0+1 (lane-linear LDS
    // write at t*32). Content involution: phys slot q holds logical slot q^(row&7),
    // identical to prior gload_lds image, so fragment reads are unchanged.
    const int arow = t >> 2;                  // 0..127
    const int r7   = arow & 7;
    const int l0   = ((t & 3) * 2) ^ r7;      // logical slot of payload0
    const int l1   = ((t & 3) * 2 + 1) ^ r7;  // logical slot of payload1

    const float* srcAf    = encf + (size_t)mt0 * 256 * 1024;
    const float* srcAf_nx = srcAf + (size_t)2048 * 1024;
    bf16* wbase    = encb + (size_t)mt0 * 256 * 1024;
    bf16* wbase_nx = wbase + (size_t)2048 * 1024;
    const float* baseA0 = srcAf;
    bf16*        wb0    = wbase;

    const int r6  = t >> 3;
    const int gsl = (t & 7) ^ (r6 & 7);
    const char* srcB = (const char*)w1bt + (size_t)(n0 + r6) * 2048 + gsl * 16;

    f32x4 ra0, ra1, ra2, ra3;   // in-flight A f32 chunk (issued 1 phase ahead)

#define ISSUE_A(BASE, KT, H) do { \
    const float* _r = (BASE) + (size_t)((H) * 128 + arow) * 1024 + (KT) * 64; \
    ra0 = *(const f32x4*)(_r + l0 * 8); \
    ra1 = *(const f32x4*)(_r + l0 * 8 + 4); \
    ra2 = *(const f32x4*)(_r + l1 * 8); \
    ra3 = *(const f32x4*)(_r + l1 * 8 + 4); \
} while (0)

#define WRITE_A(D, H, WBASE, KT) do { \
    bf16x8 _p0, _p1; \
    _p0[0]=(bf16)ra0[0]; _p0[1]=(bf16)ra0[1]; _p0[2]=(bf16)ra0[2]; _p0[3]=(bf16)ra0[3]; \
    _p0[4]=(bf16)ra1[0]; _p0[5]=(bf16)ra1[1]; _p0[6]=(bf16)ra1[2]; _p0[7]=(bf16)ra1[3]; \
    _p1[0]=(bf16)ra2[0]; _p1[1]=(bf16)ra2[1]; _p1[2]=(bf16)ra2[2]; _p1[3]=(bf16)ra2[3]; \
    _p1[4]=(bf16)ra3[0]; _p1[5]=(bf16)ra3[1]; _p1[6]=(bf16)ra3[2]; _p1[7]=(bf16)ra3[3]; \
    char* _w = smem + (D) * 32768 + (H) * 16384 + t * 32; \
    *(bf16x8*)_w = _p0; \
    *(bf16x8*)(_w + 16) = _p1; \
    if (wb) { \
        bf16* _g = (WBASE) + (size_t)((H) * 128 + arow) * 1024 + (KT) * 64; \
        *(bf16x8*)(_g + l0 * 8) = _p0; \
        *(bf16x8*)(_g + l1 * 8) = _p1; \
    } \
} while (0)

#define STAGE_B(D, H, KT) do { \
    const char* _s = srcB + (size_t)(H) * 262144 + (size_t)(KT) * 128; \
    __builtin_amdgcn_global_load_lds((const __attribute__((address_space(1))) unsigned int*)_s, \
        (__attribute__((address_space(3))) unsigned int*)(smem + 65536 + (D) * 32768 + (H) * 16384 + w * 1024), 16, 0, 0); \
    __builtin_amdgcn_global_load_lds((const __attribute__((address_space(1))) unsigned int*)(_s + 131072), \
        (__attribute__((address_space(3))) unsigned int*)(smem + 65536 + (D) * 32768 + (H) * 16384 + 8192 + w * 1024), 16, 0, 0); \
} while (0)

    const int rbA = wr * 128 + l15;
    const int rbB = wc * 64 + l15;
    const int sK0 = (g ^ (l15 & 7)) << 4;
    const int sK1 = sK0 ^ 64;
    const char* pA0 = smem + rbA * 128 + sK0;          // kk=0
    const char* pA1 = smem + rbA * 128 + sK1;          // kk=1
    const char* pB0 = smem + 65536 + rbB * 128 + sK0;
    const char* pB1 = smem + 65536 + rbB * 128 + sK1;

    f32x4 acc[8][4] = {};
    bf16x8 fa[4], fb[4];

    float wv[4];
    int gcol[4];
#pragma unroll
    for (int n = 0; n < 4; ++n) {
        gcol[n] = n0 + wc * 64 + n * 16 + l15;
        wv[n] = w2[gcol[n]];
    }

    // prologue: A tile0 -> buf0 (reg-staged), B tile0 -> buf0, B tile1 -> buf1
    ISSUE_A(srcAf, 0, 0);
    WRITE_A(0, 0, wbase, 0);
    ISSUE_A(srcAf, 0, 1);
    WRITE_A(0, 1, wbase, 0);
    STAGE_B(0, 0, 0); STAGE_B(0, 1, 0);
    STAGE_B(1, 0, 1); STAGE_B(1, 1, 1);
    VMC4;                         // B-buf0 landed; B-buf1 (4 ops) in flight
    ISSUE_A(srcAf, 1, 0);         // prime ph1 write (tile1 h0)
    LGKM0;                        // drain prologue ds_writes
    SBAR;

#pragma unroll 1
    for (int j = 0; j < 4; ++j) {
#pragma unroll 1
        for (int i = 0; i < 8; ++i) {
            const int st1 = 2 * i + 1;
            const int st2 = (i == 7) ? 0 : 2 * i + 2;
            const int st3 = (i == 7) ? 1 : 2 * i + 3;
            const bool lastI = (i == 7);
            const float* fA2 = lastI ? ((j < 3) ? srcAf_nx : baseA0) : srcAf;
            bf16*        wb2 = lastI ? ((j < 3) ? wbase_nx : wb0)   : wbase;

            // ph1: write A-buf1-h0 (tile st1, regs from prev ph8); issue A for ph2
            WRITE_A(1, 0, wbase, st1);
            ISSUE_A(srcAf, st1, 1);
            rdA4<0, 0>(pA0, fa); rdB4<0>(pB0, fb);
            SBAR; LGKM0; PRIO1; mfma16<0>(fa, fb, acc); PRIO0; SBAR;
            // ph2: write A-buf1-h1
            WRITE_A(1, 1, wbase, st1);
            rdA4<0, 1>(pA0, fa);
            SBAR; LGKM0; PRIO1; mfma16<1>(fa, fb, acc); PRIO0; SBAR;
            // ph3: no stage
            rdA4<0, 0>(pA1, fa); rdB4<0>(pB1, fb);
            SBAR; LGKM0; PRIO1; mfma16<0>(fa, fb, acc); PRIO0; SBAR;
            // ph4: stage B-buf0-h0 (tile st2)
            STAGE_B(0, 0, st2);
            rdA4<0, 1>(pA1, fa);
            SBAR; LGKM0; PRIO1; mfma16<1>(fa, fb, acc); PRIO0; SBAR;
            // ph5: issue A (st2 h0, for ph6); stage B-buf0-h1
            ISSUE_A(fA2, st2, 0);
            STAGE_B(0, 1, st2);
            rdA4<1, 0>(pA0, fa); rdB4<1>(pB0, fb);
            SBAR; LGKM0; PRIO1; mfma16<0>(fa, fb, acc); PRIO0; SBAR;
            // ph6: write A-buf0-h0 (tile st2); issue A for ph7
            WRITE_A(0, 0, wb2, st2);
            ISSUE_A(fA2, st2, 1);
            rdA4<1, 1>(pA0, fa);
            SBAR; LGKM0; PRIO1; mfma16<1>(fa, fb, acc); PRIO0; SBAR;
            // ph7: write A-buf0-h1
            WRITE_A(0, 1, wb2, st2);
            rdA4<1, 0>(pA1, fa); rdB4<1>(pB1, fb);
            SBAR; LGKM0; PRIO1; mfma16<0>(fa, fb, acc); PRIO0; SBAR;
            // ph8: issue A (st3 h0, for next ph1); stage B-buf1 h0+h1 (tile st3)
            ISSUE_A((lastI ? ((j < 3) ? srcAf_nx : baseA0) : srcAf), st3, 0);
            STAGE_B(1, 0, st3); STAGE_B(1, 1, st3);
            rdA4<1, 1>(pA1, fa);
            SBAR; LGKM0; PRIO1; mfma16<1>(fa, fb, acc); PRIO0; SBAR;
        }

        // epilogue for assignment j
        const int m0j = (mt0 + 8 * j) * 256;
        const int bj  = m0j >> 11;
        float cv[4];
#pragma unroll
        for (int n = 0; n < 4; ++n) cv[n] = cvec[bj * 1024 + gcol[n]];
#pragma unroll
        for (int m = 0; m < 8; ++m) {
#pragma unroll
            for (int r = 0; r < 4; ++r) {
                float s = 0.f;
#pragma unroll
                for (int n = 0; n < 4; ++n)
                    s += fast_tanh(acc[m][n][r] + cv[n]) * wv[n];
                s += __shfl_xor(s, 1); s += __shfl_xor(s, 2);
                s += __shfl_xor(s, 4); s += __shfl_xor(s, 8);
                if (l15 == 0)
                    atomicAdd(&ebuf[m0j + wr * 128 + m * 16 + g * 4 + r], s);
            }
        }
#pragma unroll
        for (int m = 0; m < 8; ++m)
#pragma unroll
            for (int n = 0; n < 4; ++n)
                acc[m][n] = f32x4{0.f, 0.f, 0.f, 0.f};

        srcAf = srcAf_nx; srcAf_nx += (size_t)2048 * 1024;
        wbase = wbase_nx; wbase_nx += (size_t)2048 * 1024;
    }
#undef ISSUE_A
#undef WRITE_A
#undef STAGE_B
}

// ================= old-path 128x128 f32-staging GEMM (fallback) =================
__global__ __launch_bounds__(256, 3) void k_gemm_e(
    const float* __restrict__ enc, const bf16* __restrict__ w1bt,
    const float* __restrict__ cvec, const float* __restrict__ w2,
    float* __restrict__ ebuf)
{
    __shared__ __align__(16) unsigned char smem[24 * 1024];
    const int t = threadIdx.x;
    const int lane = t & 63;
    const int w = t >> 6;
    const int wr = w >> 1, wc = w & 1;
    const int l15 = lane & 15, g = lane >> 4;

    unsigned raw = blockIdx.x;
    unsigned swz = (raw & 7u) * 512u + (raw >> 3);
    const int nt = swz & 7, mt = swz >> 3;
    const int m0 = mt * 128, n0 = nt * 128;
    const int b = m0 >> 11;

    int rowA = (t >> 3);
    int slotA = (t & 7) ^ (rowA & 7);
    const char* gA0 = (const char*)enc + (size_t)(m0 + rowA) * 4096 + slotA * 16;
    int rowB = (t >> 2);
    int slotB = (t & 3) ^ ((t >> 3) & 3);
    const char* gB0 = (const char*)w1bt + (size_t)(n0 + rowB) * 2048 + slotB * 16;

    int rowA0 = wr * 64 + l15;
    unsigned offA0 = (unsigned)rowA0 * 128 + ((((2 * g)) ^ (l15 & 7)) << 4);
    int rowB0 = wc * 64 + l15;
    unsigned offB0 = 16384u + (unsigned)rowB0 * 64 + (((g ^ ((l15 >> 1) & 3))) << 4);

    f32x4 acc[4][4] = {};

    for (int kt = 0; kt < 32; ++kt) {
        const char* pa = gA0 + kt * 128;
        const char* pb = gB0 + kt * 64;
#pragma unroll
        for (int c = 0; c < 4; ++c)
            __builtin_amdgcn_global_load_lds(
                (const __attribute__((address_space(1))) unsigned int*)(pa + (size_t)c * 131072),
                (__attribute__((address_space(3))) unsigned int*)(smem + c * 4096 + w * 1024), 16, 0, 0);
#pragma unroll
        for (int c = 0; c < 2; ++c)
            __builtin_amdgcn_global_load_lds(
                (const __attribute__((address_space(1))) unsigned int*)(pb + (size_t)c * 131072),
                (__attribute__((address_space(3))) unsigned int*)(smem + 16384 + c * 4096 + w * 1024), 16, 0, 0);
        __syncthreads();

        bf16x8 af[4], bfr[4];
#pragma unroll
        for (int m = 0; m < 4; ++m) {
            unsigned o0 = offA0 + m * 2048;
            f32x4 lo = *(const f32x4*)(smem + o0);
            f32x4 hi = *(const f32x4*)(smem + (o0 ^ 16u));
            bf16x8 a;
            a[0] = (bf16)lo[0]; a[1] = (bf16)lo[1]; a[2] = (bf16)lo[2]; a[3] = (bf16)lo[3];
            a[4] = (bf16)hi[0]; a[5] = (bf16)hi[1]; a[6] = (bf16)hi[2]; a[7] = (bf16)hi[3];
            af[m] = a;
        }
#pragma unroll
        for (int n = 0; n < 4; ++n)
            bfr[n] = *(const bf16x8*)(smem + (offB0 + n * 1024));
#pragma unroll
        for (int m = 0; m < 4; ++m)
#pragma unroll
            for (int n = 0; n < 4; ++n)
                acc[m][n] = __builtin_amdgcn_mfma_f32_16x16x32_bf16(af[m], bfr[n], acc[m][n], 0, 0, 0);
        __syncthreads();
    }

    float cv[4], wv[4];
#pragma unroll
    for (int n = 0; n < 4; ++n) {
        int gcol = n0 + wc * 64 + n * 16 + l15;
        cv[n] = cvec[b * 1024 + gcol];
        wv[n] = w2[gcol];
    }
#pragma unroll
    for (int m = 0; m < 4; ++m) {
#pragma unroll
        for (int r = 0; r < 4; ++r) {
            float s = 0.f;
#pragma unroll
            for (int n = 0; n < 4; ++n)
                s += fast_tanh(acc[m][n][r] + cv[n]) * wv[n];
            s += __shfl_xor(s, 1); s += __shfl_xor(s, 2);
            s += __shfl_xor(s, 4); s += __shfl_xor(s, 8);
            if (l15 == 0)
                atomicAdd(&ebuf[m0 + wr * 64 + m * 16 + g * 4 + r], s);
        }
    }
}

// ---------------- softmax ----------------
__global__ void k_softmax(const float* __restrict__ ebuf, float* __restrict__ alpha) {
    int bb = blockIdx.x, t = threadIdx.x;
    __shared__ float red[4], red2[4];
    float v[8];
    float mx = -1e30f;
#pragma unroll
    for (int i = 0; i < 8; ++i) { v[i] = ebuf[bb * 2048 + i * 256 + t]; mx = fmaxf(mx, v[i]); }
    for (int o = 32; o > 0; o >>= 1) mx = fmaxf(mx, __shfl_xor(mx, o));
    if ((t & 63) == 0) red[t >> 6] = mx;
    __syncthreads();
    mx = fmaxf(fmaxf(red[0], red[1]), fmaxf(red[2], red[3]));
    float sum = 0.f;
#pragma unroll
    for (int i = 0; i < 8; ++i) { v[i] = __expf(v[i] - mx); sum += v[i]; }
    for (int o = 32; o > 0; o >>= 1) sum += __shfl_xor(sum, o);
    if ((t & 63) == 0) red2[t >> 6] = sum;
    __syncthreads();
    sum = red2[0] + red2[1] + red2[2] + red2[3];
    float inv = 1.f / sum;
#pragma unroll
    for (int i = 0; i < 8; ++i) alpha[bb * 2048 + i * 256 + t] = v[i] * inv;
}

// ---------------- context from bf16 enc (written by GEMM) ----------------
__global__ void k_ctx_partial_b(const bf16* __restrict__ encb, const float* __restrict__ alpha,
                                float* __restrict__ ctxp) {
    int bid = blockIdx.x;                     // 512 = 32 b x 16 sc
    int bb = bid >> 4, sc = bid & 15;
    int t = threadIdx.x;                      // 256
    __shared__ float al[128];
    __shared__ float red[128 * 8];
    if (t < 128) al[t] = alpha[bb * 2048 + sc * 128 + t];
    __syncthreads();
    int d0 = (t & 127) * 8;
    int sp = t >> 7;
    float acc[8] = {};
    const bf16* base = encb + ((size_t)bb * 2048 + sc * 128 + sp) * 1024 + d0;
    for (int s = 0; s < 128; s += 2) {
        bf16x8 v = *(const bf16x8*)(base + (size_t)s * 1024);
        float a = al[s + sp];
#pragma unroll
        for (int k = 0; k < 8; ++k) acc[k] += a * (float)v[k];
    }
    if (sp == 1) {
#pragma unroll
        for (int k = 0; k < 8; ++k) red[(t & 127) * 8 + k] = acc[k];
    }
    __syncthreads();
    if (sp == 0) {
        float* o = ctxp + (size_t)bid * 1024 + d0;
#pragma unroll
        for (int k = 0; k < 8; ++k) o[k] = acc[k] + red[t * 8 + k];
    }
}

// ---------------- fallback f32 context ----------------
__global__ void k_ctx_partial(const float* __restrict__ enc, const float* __restrict__ alpha,
                              float* __restrict__ ctxp) {
    int bid = blockIdx.x;
    int bb = bid >> 4, sc = bid & 15;
    int t = threadIdx.x;
    __shared__ float al[128];
    if (t < 128) al[t] = alpha[bb * 2048 + sc * 128 + t];
    __syncthreads();
    f32x4 acc = {0.f, 0.f, 0.f, 0.f};
    const f32x4* base = (const f32x4*)(enc + ((size_t)bb * 2048 + sc * 128) * 1024) + t;
    for (int s = 0; s < 128; ++s) {
        f32x4 vv = base[(size_t)s * 256];
        acc += vv * al[s];
    }
    *((f32x4*)(ctxp + (size_t)bid * 1024) + t) = acc;
}

__global__ void k_ctx_reduce(const float* __restrict__ ctxp, float* __restrict__ out) {
    int i = blockIdx.x * 256 + threadIdx.x;
    int bb = i >> 10, d = i & 1023;
    float s = 0.f;
#pragma unroll
    for (int sc = 0; sc < 16; ++sc) s += ctxp[((size_t)(bb * 16 + sc)) * 1024 + d];
    out[i] = s;
}

extern "C" void kernel_launch(void* const* d_in, const int* in_sizes, int n_in,
                              void* d_out, int out_size, void* d_ws, size_t ws_size,
                              hipStream_t stream) {
    const float* hid = (const float*)d_in[0];
    const float* enc = (const float*)d_in[1];
    const float* W1  = (const float*)d_in[2];
    const float* b1  = (const float*)d_in[3];
    const float* w2  = (const float*)d_in[4];
    float* out = (float*)d_out;
    char* ws = (char*)d_ws;

    if (ws_size >= N_TOTAL) {
        bf16*  encb  = (bf16*)(ws + N_ENCB);
        bf16*  w1bt  = (bf16*)(ws + N_W1BT);
        float* cvec  = (float*)(ws + N_C);
        float* ebuf  = (float*)(ws + N_E);
        float* alpha = (float*)(ws + N_ALPHA);
        float* ctxp  = (float*)(ws + N_CTXP);

        hipMemsetAsync(ebuf, 0, 65536 * sizeof(float), stream);
        k_w1t<<<dim3(32, 32), dim3(32, 8), 0, stream>>>(W1, w1bt);
        k_cvec_init<<<128, 256, 0, stream>>>(b1, cvec);
        k_hid_atomic<<<dim3(4, 32), 256, 0, stream>>>(hid, W1, cvec);
        k_gemm8<<<256, 512, 0, stream>>>(enc, w1bt, cvec, w2, ebuf, encb);
        k_softmax<<<32, 256, 0, stream>>>(ebuf, alpha);
        k_ctx_partial_b<<<512, 256, 0, stream>>>(encb, alpha, ctxp);
        k_ctx_reduce<<<128, 256, 0, stream>>>(ctxp, out);
    } else {
        bf16*  w1bt  = (bf16*)(ws + O_W1BT);
        float* cvec  = (float*)(ws + O_C);
        float* ebuf  = (float*)(ws + O_E);
        float* alpha = (float*)(ws + O_ALPHA);
        float* hidp  = (float*)(ws + O_HIDP);
        float* ctxp  = (float*)(ws + O_CTXP);

        hipMemsetAsync(ebuf, 0, 65536 * sizeof(float), stream);
        k_hid_partial<<<dim3(4, 8), 256, 0, stream>>>(hid, W1, hidp);
        k_w1t<<<dim3(32, 32), dim3(32, 8), 0, stream>>>(W1, w1bt);
        k_hid_reduce<<<128, 256, 0, stream>>>(hidp, b1, cvec);
        k_gemm_e<<<4096, 256, 0, stream>>>(enc, w1bt, cvec, w2, ebuf);
        k_softmax<<<32, 256, 0, stream>>>(ebuf, alpha);
        k_ctx_partial<<<512, 256, 0, stream>>>(enc, alpha, ctxp);
        k_ctx_reduce<<<128, 256, 0, stream>>>(ctxp, out);
    }
}

// Round 9
// 262.968 us; speedup vs baseline: 1.3440x; 1.3440x over previous
//
#include <hip/hip_runtime.h>
#include <hip/hip_bf16.h>
#include <cstdint>

typedef __bf16 bf16;
typedef __bf16 bf16x8 __attribute__((ext_vector_type(8)));
typedef float  f32x4  __attribute__((ext_vector_type(4)));

// ---------- new-path workspace layout (needs >= 140113920 B) ----------
#define N_ENCB   0u            // 64M bf16 = 128 MB
#define N_W1BT   134217728u    // 2 MB
#define N_C      136314880u    // 128 KB
#define N_E      136445952u    // 256 KB
#define N_ALPHA  136707072u    // 256 KB
#define N_HIDP   136968192u    // 1 MB (unused in new path)
#define N_CTXP   138016768u    // 2 MB
#define N_TOTAL  140113920ull

// ---------- old-path (fallback) layout ----------
#define O_W1BT   0u
#define O_C      2097152u
#define O_E      2228224u
#define O_ALPHA  2490368u
#define O_HIDP   2752512u
#define O_CTXP   3801088u

// ---------------- enc f32 -> bf16 ----------------
__global__ void k_convert(const float* __restrict__ in, bf16* __restrict__ out) {
    size_t i = ((size_t)blockIdx.x * 256 + threadIdx.x) * 8;
    const size_t stride = (size_t)2048 * 256 * 8;
    for (; i < 67108864ull; i += stride) {
        f32x4 a = *(const f32x4*)(in + i);
        f32x4 b = *(const f32x4*)(in + i + 4);
        bf16x8 o;
        o[0]=(bf16)a[0]; o[1]=(bf16)a[1]; o[2]=(bf16)a[2]; o[3]=(bf16)a[3];
        o[4]=(bf16)b[0]; o[5]=(bf16)b[1]; o[6]=(bf16)b[2]; o[7]=(bf16)b[3];
        *(bf16x8*)(out + i) = o;
    }
}

// ---------------- cvec = b1 (broadcast per batch) ----------------
__global__ void k_cvec_init(const float* __restrict__ b1, float* __restrict__ cvec) {
    int i = blockIdx.x * 256 + threadIdx.x;   // 32768
    cvec[i] = b1[i & 1023];
}

// ---------------- hid_proj: atomic accumulate into cvec ----------------
__global__ void k_hid_atomic(const float* __restrict__ hid, const float* __restrict__ W1,
                             float* __restrict__ cvec) {
    int e = blockIdx.x * 256 + threadIdx.x;   // grid (4, 32)
    int dch = blockIdx.y;
    float acc[32];
#pragma unroll
    for (int b = 0; b < 32; ++b) acc[b] = 0.f;
    int d0 = dch * 32;
#pragma unroll 4
    for (int dd = 0; dd < 32; ++dd) {
        int d = d0 + dd;
        float w = W1[(size_t)(1024 + d) * 1024 + e];
#pragma unroll
        for (int b = 0; b < 32; ++b) acc[b] += hid[b * 1024 + d] * w;
    }
#pragma unroll
    for (int b = 0; b < 32; ++b) atomicAdd(&cvec[b * 1024 + e], acc[b]);
}

// ---------------- fallback hid_proj ----------------
__global__ void k_hid_partial(const float* __restrict__ hid, const float* __restrict__ W1,
                              float* __restrict__ hidp) {
    int e = blockIdx.x * 256 + threadIdx.x;
    int dch = blockIdx.y;
    float acc[32];
#pragma unroll
    for (int b = 0; b < 32; ++b) acc[b] = 0.f;
    int d0 = dch * 128;
    for (int dd = 0; dd < 128; ++dd) {
        int d = d0 + dd;
        float w = W1[(size_t)(1024 + d) * 1024 + e];
#pragma unroll
        for (int b = 0; b < 32; ++b) acc[b] += hid[b * 1024 + d] * w;
    }
#pragma unroll
    for (int b = 0; b < 32; ++b) hidp[((size_t)dch * 32 + b) * 1024 + e] = acc[b];
}

__global__ void k_hid_reduce(const float* __restrict__ hidp, const float* __restrict__ b1,
                             float* __restrict__ cvec) {
    int i = blockIdx.x * 256 + threadIdx.x;
    int e = i & 1023;
    float s = b1[e];
#pragma unroll
    for (int dch = 0; dch < 8; ++dch) s += hidp[(size_t)dch * 32768 + i];
    cvec[i] = s;
}

// ---------------- W1_enc -> w1bt (n x k) bf16 ----------------
__global__ void k_w1t(const float* __restrict__ W1, bf16* __restrict__ w1bt) {
    __shared__ float tile[32][33];
    int tx = threadIdx.x, ty = threadIdx.y;
    int bx = blockIdx.x, by = blockIdx.y;
#pragma unroll
    for (int i = 0; i < 4; ++i)
        tile[ty + i * 8][tx] = W1[(size_t)(by * 32 + ty + i * 8) * 1024 + bx * 32 + tx];
    __syncthreads();
#pragma unroll
    for (int i = 0; i < 4; ++i)
        w1bt[(size_t)(bx * 32 + ty + i * 8) * 1024 + by * 32 + tx] = (bf16)tile[tx][ty + i * 8];
}

__device__ inline float fast_tanh(float x) {
    float e2 = __expf(2.f * x);
    return 1.f - 2.f / (e2 + 1.f);
}

// ================= persistent 256x256 bf16 GEMM, 4-region schedule (R4-best) =========
#define SBAR  __builtin_amdgcn_s_barrier()
#define VMC4  asm volatile("s_waitcnt vmcnt(4)" ::: "memory")
#define PRIO1 __builtin_amdgcn_s_setprio(1)
#define PRIO0 __builtin_amdgcn_s_setprio(0)

template<int D, int MH>
__device__ __forceinline__ void rdA(const char* pA0, const char* pA1, bf16x8 (&bA)[4][2]) {
#pragma unroll
    for (int m = 0; m < 4; ++m) {
        bA[m][0] = *(const bf16x8*)(pA0 + D * 32768 + MH * 8192 + m * 2048);
        bA[m][1] = *(const bf16x8*)(pA1 + D * 32768 + MH * 8192 + m * 2048);
    }
}
template<int D, int N0>
__device__ __forceinline__ void rdB(const char* pB0, const char* pB1, bf16x8 (&bB)[4][2]) {
#pragma unroll
    for (int n = 0; n < 2; ++n) {
        bB[N0 + n][0] = *(const bf16x8*)(pB0 + D * 32768 + (N0 + n) * 2048);
        bB[N0 + n][1] = *(const bf16x8*)(pB1 + D * 32768 + (N0 + n) * 2048);
    }
}
// kk-outer: dependent MFMA pairs spaced by 8 independent instructions
template<int MH, int NH>
__device__ __forceinline__ void mfmaQ(bf16x8 (&bA)[4][2], bf16x8 (&bB)[4][2], f32x4 (&acc)[8][4]) {
#pragma unroll
    for (int kk = 0; kk < 2; ++kk)
#pragma unroll
        for (int m = 0; m < 4; ++m)
#pragma unroll
            for (int n = 0; n < 2; ++n)
                acc[MH * 4 + m][NH * 2 + n] = __builtin_amdgcn_mfma_f32_16x16x32_bf16(
                    bA[m][kk], bB[NH * 2 + n][kk], acc[MH * 4 + m][NH * 2 + n], 0, 0, 0);
}

__global__ __launch_bounds__(512, 1) void k_gemm8(
    const bf16* __restrict__ encb, const bf16* __restrict__ w1bt,
    const float* __restrict__ cvec, const float* __restrict__ w2,
    float* __restrict__ ebuf)
{
    __shared__ __align__(16) char smem[131072];
    const int t = threadIdx.x;
    const int lane = t & 63;
    const int w  = t >> 6;
    const int wr = w >> 2;
    const int wc = w & 3;
    const int l15 = lane & 15, g = (lane >> 4) & 3;

    // persistent: nt constant per block (B panel fixed), mt steps by 8 per assignment
    unsigned bidx = blockIdx.x;               // 256 blocks
    unsigned swz0 = (bidx & 7u) * 128u + (bidx >> 3);
    const int nt  = swz0 & 3;
    const int mt0 = swz0 >> 2;
    const int n0  = nt * 256;

    const int r6  = t >> 3;
    const int gsl = (t & 7) ^ (r6 & 7);
    const char* srcA    = (const char*)encb + (size_t)(mt0 * 256 + r6) * 2048 + gsl * 16;
    const char* srcA_nx = srcA + (size_t)2048 * 2048;
    const char* srcB    = (const char*)w1bt + (size_t)(n0 + r6) * 2048 + gsl * 16;

#define STAGE_A(SRC, D, H, KT) do { \
    const char* _s = (SRC) + (size_t)(H) * 262144 + (size_t)(KT) * 128; \
    __builtin_amdgcn_global_load_lds((const __attribute__((address_space(1))) unsigned int*)_s, \
        (__attribute__((address_space(3))) unsigned int*)(smem + (D) * 32768 + (H) * 16384 + w * 1024), 16, 0, 0); \
    __builtin_amdgcn_global_load_lds((const __attribute__((address_space(1))) unsigned int*)(_s + 131072), \
        (__attribute__((address_space(3))) unsigned int*)(smem + (D) * 32768 + (H) * 16384 + 8192 + w * 1024), 16, 0, 0); \
} while (0)
#define STAGE_B(D, H, KT) do { \
    const char* _s = srcB + (size_t)(H) * 262144 + (size_t)(KT) * 128; \
    __builtin_amdgcn_global_load_lds((const __attribute__((address_space(1))) unsigned int*)_s, \
        (__attribute__((address_space(3))) unsigned int*)(smem + 65536 + (D) * 32768 + (H) * 16384 + w * 1024), 16, 0, 0); \
    __builtin_amdgcn_global_load_lds((const __attribute__((address_space(1))) unsigned int*)(_s + 131072), \
        (__attribute__((address_space(3))) unsigned int*)(smem + 65536 + (D) * 32768 + (H) * 16384 + 8192 + w * 1024), 16, 0, 0); \
} while (0)

    const int rbA = wr * 128 + l15;
    const int rbB = wc * 64 + l15;
    const int sK0 = (g ^ (l15 & 7)) << 4;
    const int sK1 = sK0 ^ 64;
    const char* pA0 = smem + rbA * 128 + sK0;
    const char* pA1 = smem + rbA * 128 + sK1;
    const char* pB0 = smem + 65536 + rbB * 128 + sK0;
    const char* pB1 = smem + 65536 + rbB * 128 + sK1;

    f32x4 acc[8][4] = {};
    bf16x8 bA[4][2], bB[4][2];

    float wv[4];
    int gcol[4];
#pragma unroll
    for (int n = 0; n < 4; ++n) {
        gcol[n] = n0 + wc * 64 + n * 16 + l15;
        wv[n] = w2[gcol[n]];
    }

    // one-time prologue: tile0 A+B -> buf0, tile1 B -> buf1 (leaves 4 B-ops in flight)
    STAGE_A(srcA, 0, 0, 0); STAGE_A(srcA, 0, 1, 0);
    STAGE_B(0, 0, 0); STAGE_B(0, 1, 0);
    STAGE_B(1, 0, 1); STAGE_B(1, 1, 1);
    VMC4; SBAR;

#pragma unroll 1
    for (int j = 0; j < 4; ++j) {
#pragma unroll 1
        for (int i = 0; i < 8; ++i) {
            const int st1 = 2 * i + 1;
            const bool last = (i == 7);
            const int st2 = last ? 0 : 2 * i + 2;
            const int st3 = last ? 1 : 2 * i + 3;
            const char* sA2 = last ? ((j < 3) ? srcA_nx : srcA) : srcA;

            // R1: buf0 MH0, all NH. 16 ds_reads + stage A(t+1)->buf1 + 32 MFMA.
            rdA<0, 0>(pA0, pA1, bA);
            rdB<0, 0>(pB0, pB1, bB);
            rdB<0, 2>(pB0, pB1, bB);
            STAGE_A(srcA, 1, 0, st1);
            STAGE_A(srcA, 1, 1, st1);
            PRIO1; mfmaQ<0, 0>(bA, bB, acc); mfmaQ<0, 1>(bA, bB, acc); PRIO0;
            SBAR;   // all waves' buf0-B reads done before R2 restages buf0-B

            // R2: buf0 MH1 (B frags reused in regs). Stage B(t+2)->buf0. Drain D1.
            rdA<0, 1>(pA0, pA1, bA);
            STAGE_B(0, 0, st2);
            STAGE_B(0, 1, st2);
            PRIO1; mfmaQ<1, 0>(bA, bB, acc); mfmaQ<1, 1>(bA, bB, acc); PRIO0;
            VMC4;   // drains prev B-buf1 + this iter's A-buf1 (12 outstanding -> 4)
            SBAR;   // buf0-A reads done before R3 restages buf0-A; buf1 visible

            // R3: buf1 MH0. Stage A(t+2)->buf0.
            rdA<1, 0>(pA0, pA1, bA);
            rdB<1, 0>(pB0, pB1, bB);
            rdB<1, 2>(pB0, pB1, bB);
            STAGE_A(sA2, 0, 0, st2);
            STAGE_A(sA2, 0, 1, st2);
            PRIO1; mfmaQ<0, 0>(bA, bB, acc); mfmaQ<0, 1>(bA, bB, acc); PRIO0;
            SBAR;   // buf1-B reads done before R4 restages buf1-B

            // R4: buf1 MH1. Stage B(t+3)->buf1. Drain D2.
            rdA<1, 1>(pA0, pA1, bA);
            STAGE_B(1, 0, st3);
            STAGE_B(1, 1, st3);
            PRIO1; mfmaQ<1, 0>(bA, bB, acc); mfmaQ<1, 1>(bA, bB, acc); PRIO0;
            VMC4;   // drains B-buf0 + A-buf0 for next iter's R1/R2
            SBAR;
        }

        // epilogue for assignment j (4 B-ops for next tile remain in flight)
        const int m0j = (mt0 + 8 * j) * 256;
        const int bj  = m0j >> 11;
        float cv[4];
#pragma unroll
        for (int n = 0; n < 4; ++n) cv[n] = cvec[bj * 1024 + gcol[n]];
#pragma unroll
        for (int m = 0; m < 8; ++m) {
#pragma unroll
            for (int r = 0; r < 4; ++r) {
                float s = 0.f;
#pragma unroll
                for (int n = 0; n < 4; ++n)
                    s += fast_tanh(acc[m][n][r] + cv[n]) * wv[n];
                s += __shfl_xor(s, 1); s += __shfl_xor(s, 2);
                s += __shfl_xor(s, 4); s += __shfl_xor(s, 8);
                if (l15 == 0)
                    atomicAdd(&ebuf[m0j + wr * 128 + m * 16 + g * 4 + r], s);
            }
        }
#pragma unroll
        for (int m = 0; m < 8; ++m)
#pragma unroll
            for (int n = 0; n < 4; ++n)
                acc[m][n] = f32x4{0.f, 0.f, 0.f, 0.f};

        srcA = srcA_nx;
        srcA_nx += (size_t)2048 * 2048;
    }
#undef STAGE_A
#undef STAGE_B
}

// ================= old-path 128x128 f32-staging GEMM (fallback) =================
__global__ __launch_bounds__(256, 3) void k_gemm_e(
    const float* __restrict__ enc, const bf16* __restrict__ w1bt,
    const float* __restrict__ cvec, const float* __restrict__ w2,
    float* __restrict__ ebuf)
{
    __shared__ __align__(16) unsigned char smem[24 * 1024];
    const int t = threadIdx.x;
    const int lane = t & 63;
    const int w = t >> 6;
    const int wr = w >> 1, wc = w & 1;
    const int l15 = lane & 15, g = lane >> 4;

    unsigned raw = blockIdx.x;
    unsigned swz = (raw & 7u) * 512u + (raw >> 3);
    const int nt = swz & 7, mt = swz >> 3;
    const int m0 = mt * 128, n0 = nt * 128;
    const int b = m0 >> 11;

    int rowA = (t >> 3);
    int slotA = (t & 7) ^ (rowA & 7);
    const char* gA0 = (const char*)enc + (size_t)(m0 + rowA) * 4096 + slotA * 16;
    int rowB = (t >> 2);
    int slotB = (t & 3) ^ ((t >> 3) & 3);
    const char* gB0 = (const char*)w1bt + (size_t)(n0 + rowB) * 2048 + slotB * 16;

    int rowA0 = wr * 64 + l15;
    unsigned offA0 = (unsigned)rowA0 * 128 + ((((2 * g)) ^ (l15 & 7)) << 4);
    int rowB0 = wc * 64 + l15;
    unsigned offB0 = 16384u + (unsigned)rowB0 * 64 + (((g ^ ((l15 >> 1) & 3))) << 4);

    f32x4 acc[4][4] = {};

    for (int kt = 0; kt < 32; ++kt) {
        const char* pa = gA0 + kt * 128;
        const char* pb = gB0 + kt * 64;
#pragma unroll
        for (int c = 0; c < 4; ++c)
            __builtin_amdgcn_global_load_lds(
                (const __attribute__((address_space(1))) unsigned int*)(pa + (size_t)c * 131072),
                (__attribute__((address_space(3))) unsigned int*)(smem + c * 4096 + w * 1024), 16, 0, 0);
#pragma unroll
        for (int c = 0; c < 2; ++c)
            __builtin_amdgcn_global_load_lds(
                (const __attribute__((address_space(1))) unsigned int*)(pb + (size_t)c * 131072),
                (__attribute__((address_space(3))) unsigned int*)(smem + 16384 + c * 4096 + w * 1024), 16, 0, 0);
        __syncthreads();

        bf16x8 af[4], bfr[4];
#pragma unroll
        for (int m = 0; m < 4; ++m) {
            unsigned o0 = offA0 + m * 2048;
            f32x4 lo = *(const f32x4*)(smem + o0);
            f32x4 hi = *(const f32x4*)(smem + (o0 ^ 16u));
            bf16x8 a;
            a[0] = (bf16)lo[0]; a[1] = (bf16)lo[1]; a[2] = (bf16)lo[2]; a[3] = (bf16)lo[3];
            a[4] = (bf16)hi[0]; a[5] = (bf16)hi[1]; a[6] = (bf16)hi[2]; a[7] = (bf16)hi[3];
            af[m] = a;
        }
#pragma unroll
        for (int n = 0; n < 4; ++n)
            bfr[n] = *(const bf16x8*)(smem + (offB0 + n * 1024));
#pragma unroll
        for (int m = 0; m < 4; ++m)
#pragma unroll
            for (int n = 0; n < 4; ++n)
                acc[m][n] = __builtin_amdgcn_mfma_f32_16x16x32_bf16(af[m], bfr[n], acc[m][n], 0, 0, 0);
        __syncthreads();
    }

    float cv[4], wv[4];
#pragma unroll
    for (int n = 0; n < 4; ++n) {
        int gcol = n0 + wc * 64 + n * 16 + l15;
        cv[n] = cvec[b * 1024 + gcol];
        wv[n] = w2[gcol];
    }
#pragma unroll
    for (int m = 0; m < 4; ++m) {
#pragma unroll
        for (int r = 0; r < 4; ++r) {
            float s = 0.f;
#pragma unroll
            for (int n = 0; n < 4; ++n)
                s += fast_tanh(acc[m][n][r] + cv[n]) * wv[n];
            s += __shfl_xor(s, 1); s += __shfl_xor(s, 2);
            s += __shfl_xor(s, 4); s += __shfl_xor(s, 8);
            if (l15 == 0)
                atomicAdd(&ebuf[m0 + wr * 64 + m * 16 + g * 4 + r], s);
        }
    }
}

// ---------------- softmax ----------------
__global__ void k_softmax(const float* __restrict__ ebuf, float* __restrict__ alpha) {
    int bb = blockIdx.x, t = threadIdx.x;
    __shared__ float red[4], red2[4];
    float v[8];
    float mx = -1e30f;
#pragma unroll
    for (int i = 0; i < 8; ++i) { v[i] = ebuf[bb * 2048 + i * 256 + t]; mx = fmaxf(mx, v[i]); }
    for (int o = 32; o > 0; o >>= 1) mx = fmaxf(mx, __shfl_xor(mx, o));
    if ((t & 63) == 0) red[t >> 6] = mx;
    __syncthreads();
    mx = fmaxf(fmaxf(red[0], red[1]), fmaxf(red[2], red[3]));
    float sum = 0.f;
#pragma unroll
    for (int i = 0; i < 8; ++i) { v[i] = __expf(v[i] - mx); sum += v[i]; }
    for (int o = 32; o > 0; o >>= 1) sum += __shfl_xor(sum, o);
    if ((t & 63) == 0) red2[t >> 6] = sum;
    __syncthreads();
    sum = red2[0] + red2[1] + red2[2] + red2[3];
    float inv = 1.f / sum;
#pragma unroll
    for (int i = 0; i < 8; ++i) alpha[bb * 2048 + i * 256 + t] = v[i] * inv;
}

// ---------------- context from bf16 enc (halves read traffic) ----------------
__global__ void k_ctx_partial_b(const bf16* __restrict__ encb, const float* __restrict__ alpha,
                                float* __restrict__ ctxp) {
    int bid = blockIdx.x;                     // 512 = 32 b x 16 sc
    int bb = bid >> 4, sc = bid & 15;
    int t = threadIdx.x;                      // 256
    __shared__ float al[128];
    __shared__ float red[128 * 8];
    if (t < 128) al[t] = alpha[bb * 2048 + sc * 128 + t];
    __syncthreads();
    int d0 = (t & 127) * 8;
    int sp = t >> 7;                          // 0/1 row parity
    float acc[8] = {};
    const bf16* base = encb + ((size_t)bb * 2048 + sc * 128 + sp) * 1024 + d0;
    for (int s = 0; s < 128; s += 2) {
        bf16x8 v = *(const bf16x8*)(base + (size_t)s * 1024);
        float a = al[s + sp];
#pragma unroll
        for (int k = 0; k < 8; ++k) acc[k] += a * (float)v[k];
    }
    if (sp == 1) {
#pragma unroll
        for (int k = 0; k < 8; ++k) red[(t & 127) * 8 + k] = acc[k];
    }
    __syncthreads();
    if (sp == 0) {
        float* o = ctxp + (size_t)bid * 1024 + d0;
#pragma unroll
        for (int k = 0; k < 8; ++k) o[k] = acc[k] + red[t * 8 + k];
    }
}

// ---------------- fallback f32 context ----------------
__global__ void k_ctx_partial(const float* __restrict__ enc, const float* __restrict__ alpha,
                              float* __restrict__ ctxp) {
    int bid = blockIdx.x;
    int bb = bid >> 4, sc = bid & 15;
    int t = threadIdx.x;
    __shared__ float al[128];
    if (t < 128) al[t] = alpha[bb * 2048 + sc * 128 + t];
    __syncthreads();
    f32x4 acc = {0.f, 0.f, 0.f, 0.f};
    const f32x4* base = (const f32x4*)(enc + ((size_t)bb * 2048 + sc * 128) * 1024) + t;
    for (int s = 0; s < 128; ++s) {
        f32x4 vv = base[(size_t)s * 256];
        acc += vv * al[s];
    }
    *((f32x4*)(ctxp + (size_t)bid * 1024) + t) = acc;
}

__global__ void k_ctx_reduce(const float* __restrict__ ctxp, float* __restrict__ out) {
    int i = blockIdx.x * 256 + threadIdx.x;
    int bb = i >> 10, d = i & 1023;
    float s = 0.f;
#pragma unroll
    for (int sc = 0; sc < 16; ++sc) s += ctxp[((size_t)(bb * 16 + sc)) * 1024 + d];
    out[i] = s;
}

extern "C" void kernel_launch(void* const* d_in, const int* in_sizes, int n_in,
                              void* d_out, int out_size, void* d_ws, size_t ws_size,
                              hipStream_t stream) {
    const float* hid = (const float*)d_in[0];
    const float* enc = (const float*)d_in[1];
    const float* W1  = (const float*)d_in[2];
    const float* b1  = (const float*)d_in[3];
    const float* w2  = (const float*)d_in[4];
    float* out = (float*)d_out;
    char* ws = (char*)d_ws;

    if (ws_size >= N_TOTAL) {
        bf16*  encb  = (bf16*)(ws + N_ENCB);
        bf16*  w1bt  = (bf16*)(ws + N_W1BT);
        float* cvec  = (float*)(ws + N_C);
        float* ebuf  = (float*)(ws + N_E);
        float* alpha = (float*)(ws + N_ALPHA);
        float* ctxp  = (float*)(ws + N_CTXP);

        hipMemsetAsync(ebuf, 0, 65536 * sizeof(float), stream);
        k_convert<<<2048, 256, 0, stream>>>(enc, encb);
        k_w1t<<<dim3(32, 32), dim3(32, 8), 0, stream>>>(W1, w1bt);
        k_cvec_init<<<128, 256, 0, stream>>>(b1, cvec);
        k_hid_atomic<<<dim3(4, 32), 256, 0, stream>>>(hid, W1, cvec);
        k_gemm8<<<256, 512, 0, stream>>>(encb, w1bt, cvec, w2, ebuf);
        k_softmax<<<32, 256, 0, stream>>>(ebuf, alpha);
        k_ctx_partial_b<<<512, 256, 0, stream>>>(encb, alpha, ctxp);
        k_ctx_reduce<<<128, 256, 0, stream>>>(ctxp, out);
    } else {
        bf16*  w1bt  = (bf16*)(ws + O_W1BT);
        float* cvec  = (float*)(ws + O_C);
        float* ebuf  = (float*)(ws + O_E);
        float* alpha = (float*)(ws + O_ALPHA);
        float* hidp  = (float*)(ws + O_HIDP);
        float* ctxp  = (float*)(ws + O_CTXP);

        hipMemsetAsync(ebuf, 0, 65536 * sizeof(float), stream);
        k_hid_partial<<<dim3(4, 8), 256, 0, stream>>>(hid, W1, hidp);
        k_w1t<<<dim3(32, 32), dim3(32, 8), 0, stream>>>(W1, w1bt);
        k_hid_reduce<<<128, 256, 0, stream>>>(hidp, b1, cvec);
        k_gemm_e<<<4096, 256, 0, stream>>>(enc, w1bt, cvec, w2, ebuf);
        k_softmax<<<32, 256, 0, stream>>>(ebuf, alpha);
        k_ctx_partial<<<512, 256, 0, stream>>>(enc, alpha, ctxp);
        k_ctx_reduce<<<128, 256, 0, stream>>>(ctxp, out);
    }
}